// Round 7
// baseline (430.294 us; speedup 1.0000x reference)
//
#include <hip/hip_runtime.h>
#include <hip/hip_bf16.h>

#define N_NODES 40000
#define N_EDGES 640000
#define R_REL 4
#define F_IN 128
#define H_DIM 128
#define NBLK 2
#define G_GRAPHS 64
#define N_OUT 10
#define MAXDEG 10
#define NSCAN_BLK ((N_NODES + 255) / 256)   // 157

typedef unsigned short u16;
typedef float f32x4 __attribute__((ext_vector_type(4)));
typedef short bf16x8 __attribute__((ext_vector_type(8)));

__device__ __forceinline__ float relu_f(float x){ return x > 0.f ? x : 0.f; }

// fp32 -> bf16 round-to-nearest-even
__device__ __forceinline__ u16 f2bf(float f){
  union { float f; unsigned int u; } v; v.f = f;
  unsigned int r = v.u + 0x7fffu + ((v.u >> 16) & 1u);
  return (u16)(r >> 16);
}
__device__ __forceinline__ float b2f(u16 u){
  union { unsigned int u; float f; } v; v.u = ((unsigned int)u) << 16; return v.f;
}
__device__ __forceinline__ float blo(unsigned v){ return b2f((u16)v); }
__device__ __forceinline__ float bhi(unsigned v){ return b2f((u16)(v >> 16)); }

// async global->LDS 16B: linear LDS dest (wave base + lane*16), swizzle carried on src
__device__ __forceinline__ void gload16(const void* g, void* l){
  __builtin_amdgcn_global_load_lds(
      (const __attribute__((address_space(1))) void*)g,
      (__attribute__((address_space(3))) void*)l, 16, 0, 0);
}

// ---------- per-(node,rel) counts ----------
__global__ void k_cnt(const int* __restrict__ dst, const int* __restrict__ et, int* __restrict__ cnt4){
  int e = blockIdx.x * blockDim.x + threadIdx.x;
  if (e >= N_EDGES) return;
  atomicAdd(&cnt4[dst[e] * R_REL + et[e]], 1);
}

// ---------- scan A ----------
__global__ __launch_bounds__(256) void k_scan_a(const int* __restrict__ cnt4, int* __restrict__ deg,
                                                int* __restrict__ row_ptr, int* __restrict__ bsum,
                                                int* __restrict__ bhist){
  __shared__ int s[256];
  __shared__ int lh[16];
  int tid = threadIdx.x;
  int i = blockIdx.x * 256 + tid;
  if (tid < 16) lh[tid] = 0;
  int d = 0;
  if (i < N_NODES){
    int4 c = *(const int4*)(cnt4 + (size_t)i * 4);
    d = c.x + c.y + c.z + c.w;
    deg[i] = d;
  }
  s[tid] = d;
  __syncthreads();
  if (i < N_NODES){
    int dc = d > MAXDEG ? MAXDEG : d;
    atomicAdd(&lh[dc], 1);
  }
  for (int o = 1; o < 256; o <<= 1){
    int t = (tid >= o) ? s[tid - o] : 0;
    __syncthreads();
    s[tid] += t;
    __syncthreads();
  }
  if (i < N_NODES) row_ptr[i] = s[tid] - d;
  if (tid == 255) bsum[blockIdx.x] = s[255];
  if (tid <= MAXDEG) bhist[blockIdx.x * (MAXDEG + 1) + tid] = lh[tid];
}

__global__ __launch_bounds__(256) void k_scan_b(int* __restrict__ bsum, int* __restrict__ bbase){
  __shared__ int s[256];
  int tid = threadIdx.x;
  int v = (tid < NSCAN_BLK) ? bsum[tid] : 0;
  s[tid] = v;
  __syncthreads();
  for (int o = 1; o < 256; o <<= 1){
    int t = (tid >= o) ? s[tid - o] : 0;
    __syncthreads();
    s[tid] += t;
    __syncthreads();
  }
  if (tid < NSCAN_BLK) bbase[tid] = s[tid] - v;
}

// scan C: finalize row_ptr, emit rel_off AND init cursor with the same start offsets
__global__ __launch_bounds__(256) void k_scan_c(int* __restrict__ row_ptr, const int* __restrict__ bbase,
                                                const int* __restrict__ cnt4, int* __restrict__ rel_off,
                                                int* __restrict__ cursor){
  int i = blockIdx.x * 256 + threadIdx.x;
  if (i < N_NODES){
    int base = row_ptr[i] + bbase[blockIdx.x];
    row_ptr[i] = base;
    int4 c = *(const int4*)(cnt4 + (size_t)i * 4);
    int4 o;
    o.x = base;
    o.y = base + c.x;
    o.z = o.y + c.y;
    o.w = o.z + c.z;
    *(int4*)(rel_off + (size_t)i * 4) = o;
    *(int4*)(cursor + (size_t)i * 4) = o;
  }
  if (i == 0) row_ptr[N_NODES] = N_EDGES;
}

// ---------- CSR fill: cursor pre-seeded with absolute starts ----------
__global__ void k_csr_fill(const int* __restrict__ src, const int* __restrict__ dst,
                           const int* __restrict__ et,
                           int* __restrict__ cursor, int* __restrict__ esrc){
  int e = blockIdx.x * blockDim.x + threadIdx.x;
  if (e >= N_EDGES) return;
  int cell = dst[e] * R_REL + et[e];
  int p = atomicAdd(&cursor[cell], 1);
  esrc[p] = src[e];
}

// ---------- degree-bucket counting sort ----------
__global__ __launch_bounds__(64) void k_bscan(const int* __restrict__ bhist, int* __restrict__ pbase,
                                              int* __restrict__ bcount, int* __restrict__ boff){
  __shared__ int cnt_s[MAXDEG + 1];
  __shared__ int off_s[MAXDEG + 1];
  int d = threadIdx.x;
  if (d <= MAXDEG){
    int run = 0;
    for (int b = 0; b < NSCAN_BLK; ++b){
      pbase[b * (MAXDEG + 1) + d] = run;
      run += bhist[b * (MAXDEG + 1) + d];
    }
    cnt_s[d] = run;
    bcount[d] = run;
  }
  __syncthreads();
  if (d == 0){
    int s = 0;
    for (int dd = 0; dd <= MAXDEG; ++dd){ off_s[dd] = s; boff[dd] = s; s += cnt_s[dd]; }
  }
  __syncthreads();
  if (d <= MAXDEG){
    int base = off_s[d];
    for (int b = 0; b < NSCAN_BLK; ++b) pbase[b * (MAXDEG + 1) + d] += base;
  }
}

__global__ __launch_bounds__(256) void k_bfill(const int* __restrict__ deg, const int* __restrict__ pbase,
                                               int* __restrict__ perm){
  __shared__ int lh[MAXDEG + 1];
  int tid = threadIdx.x;
  if (tid <= MAXDEG) lh[tid] = 0;
  __syncthreads();
  int i = blockIdx.x * 256 + tid;
  if (i < N_NODES){
    int d = deg[i]; if (d > MAXDEG) d = MAXDEG;
    int lpos = atomicAdd(&lh[d], 1);
    perm[pbase[blockIdx.x * (MAXDEG + 1) + d] + lpos] = i;
  }
}

// ---------- all weight tensors: fp32 -> bf16 transposed ----------
__global__ __launch_bounds__(256) void k_cvtW_all(const float* __restrict__ s0, const float* __restrict__ s1,
                                                  const float* __restrict__ s2, const float* __restrict__ s3,
                                                  const float* __restrict__ s4,
                                                  u16* __restrict__ d0, u16* __restrict__ d1,
                                                  u16* __restrict__ d2, u16* __restrict__ d3,
                                                  u16* __restrict__ d4){
  __shared__ float s[32][33];
  int b = blockIdx.x;
  int m = b >> 4, tile = b & 15;
  const float* S; u16* D; int base;
  if (m < 1){ S = s0; D = d0; base = m; }
  else if (m < 9){ S = s1; D = d1; base = m - 1; }
  else if (m < 11){ S = s2; D = d2; base = m - 9; }
  else if (m < 33){ S = s3; D = d3; base = m - 11; }
  else { S = s4; D = d4; base = m - 33; }
  S += (size_t)base * 16384;
  D += (size_t)base * 16384;
  int tr = (tile >> 2) * 32, tc = (tile & 3) * 32;
  int c = threadIdx.x & 31, r0 = threadIdx.x >> 5;
  #pragma unroll
  for (int i = 0; i < 4; ++i){
    int r = r0 + i * 8;
    s[r][c] = S[(size_t)(tr + r) * 128 + tc + c];
  }
  __syncthreads();
  #pragma unroll
  for (int i = 0; i < 4; ++i){
    int r = r0 + i * 8;
    D[(size_t)(tc + r) * 128 + tr + c] = f2bf(s[c][r]);
  }
}

// ---------- x fp32 -> bf16 ----------
__global__ void k_cvtx(const float* __restrict__ x, u16* __restrict__ xb){
  int t = blockIdx.x * 256 + threadIdx.x;
  if (t >= (N_NODES * H_DIM) / 4) return;
  float4 v = ((const float4*)x)[t];
  uint2 o = make_uint2((unsigned)f2bf(v.x) | ((unsigned)f2bf(v.y) << 16),
                       (unsigned)f2bf(v.z) | ((unsigned)f2bf(v.w) << 16));
  ((uint2*)xb)[t] = o;
}

// ======== LDS-staged fused MFMA kernels ========
// Tile: 32 rows x 128 cols, 512 threads (8 waves), wave w = col-tile w.
// A-tiles live in LDS with XOR swizzle byte^=((row&7)<<4).
// Aggregated tiles are ds_written directly (swizzled); root/static tiles staged
// via global_load_lds with inverse-swizzled source.

// ---------- gemm0: hb = bf16(relu(xb @ W0T + b0)), K=128 ----------
__global__ __launch_bounds__(512) void k_gemm0(const u16* __restrict__ xb, const u16* __restrict__ wt,
                                               const float* __restrict__ bias, u16* __restrict__ hbo){
  __shared__ u16 lds[32][128];
  int tid = threadIdx.x;
  int w = tid >> 6, lane = tid & 63;
  int m0 = blockIdx.x * 32;
  int rg = lane >> 4, cb = (lane & 15) << 4;
  int srow = w * 4 + rg;
  int swcb = cb ^ ((srow & 7) << 4);
  gload16(xb + (size_t)(m0 + srow) * F_IN + (swcb >> 1), &lds[w * 4][0]);
  __syncthreads();

  int arow = lane & 15, kg = lane >> 4;
  int col = w * 16 + arow;
  f32x4 acc[2];
  acc[0] = (f32x4){0.f, 0.f, 0.f, 0.f};
  acc[1] = (f32x4){0.f, 0.f, 0.f, 0.f};
  bf16x8 b[4];
  #pragma unroll
  for (int kk = 0; kk < 4; ++kk)
    b[kk] = *(const bf16x8*)(wt + (size_t)col * F_IN + kk * 32 + kg * 8);
  #pragma unroll
  for (int rt = 0; rt < 2; ++rt){
    int row = rt * 16 + arow;
    const char* base = (const char*)&lds[0][0] + row * 256;
    int sx = (row & 7) << 4;
    #pragma unroll
    for (int kk = 0; kk < 4; ++kk){
      bf16x8 a = *(const bf16x8*)(base + ((kk * 64 + kg * 16) ^ sx));
      acc[rt] = __builtin_amdgcn_mfma_f32_16x16x32_bf16(a, b[kk], acc[rt], 0, 0, 0);
    }
  }
  float bb = bias[col];
  #pragma unroll
  for (int rt = 0; rt < 2; ++rt)
    #pragma unroll
    for (int j = 0; j < 4; ++j){
      int gr = m0 + rt * 16 + kg * 4 + j;
      hbo[(size_t)gr * H_DIM + col] = f2bf(relu_f(acc[rt][j] + bb));
    }
}

// ---------- fused RGCN: in-kernel per-relation mean -> LDS, then K=5*128 MFMA ----------
__global__ __launch_bounds__(512) void k_rgcn_fused(const u16* __restrict__ hb,
                                                    const int* __restrict__ rel_off,
                                                    const int* __restrict__ row_ptr,
                                                    const int* __restrict__ esrc,
                                                    const u16* __restrict__ wrel, const u16* __restrict__ wroot,
                                                    const float* __restrict__ bias, u16* __restrict__ hbo){
  __shared__ u16 lds[5][32][128];   // 40 KB: 4 relation means + root
  int tid = threadIdx.x;
  int w = tid >> 6, lane = tid & 63;
  int m0 = blockIdx.x * 32;
  // stage root rows
  {
    int rg = lane >> 4, cb = (lane & 15) << 4;
    int srow = w * 4 + rg;
    int swcb = cb ^ ((srow & 7) << 4);
    gload16(hb + (size_t)(m0 + srow) * H_DIM + (swcb >> 1), &lds[4][w * 4][0]);
  }
  // aggregate: wave w owns rows w*4 .. w*4+3 (lanes = 128 cols, 2 per lane)
  #pragma unroll
  for (int i = 0; i < 4; ++i){
    int row = w * 4 + i;
    int node = m0 + row;
    int4 ro = *(const int4*)(rel_off + (size_t)node * 4);
    int nend = row_ptr[node + 1];
    int begs[5] = {ro.x, ro.y, ro.z, ro.w, nend};
    int sx = (row & 7) << 4;
    char* ldsb = (char*)&lds[0][0][0];
    #pragma unroll
    for (int r = 0; r < R_REL; ++r){
      int beg = begs[r], end = begs[r + 1];
      float a0 = 0.f, a1 = 0.f;
      int e = beg;
      for (; e + 4 <= end; e += 4){
        int s0 = esrc[e], s1 = esrc[e + 1], s2 = esrc[e + 2], s3 = esrc[e + 3];
        unsigned v0 = *(const unsigned*)(hb + (size_t)s0 * H_DIM + lane * 2);
        unsigned v1 = *(const unsigned*)(hb + (size_t)s1 * H_DIM + lane * 2);
        unsigned v2 = *(const unsigned*)(hb + (size_t)s2 * H_DIM + lane * 2);
        unsigned v3 = *(const unsigned*)(hb + (size_t)s3 * H_DIM + lane * 2);
        a0 += blo(v0) + blo(v1) + blo(v2) + blo(v3);
        a1 += bhi(v0) + bhi(v1) + bhi(v2) + bhi(v3);
      }
      for (; e < end; ++e){
        unsigned v = *(const unsigned*)(hb + (size_t)esrc[e] * H_DIM + lane * 2);
        a0 += blo(v); a1 += bhi(v);
      }
      int c = end - beg;
      float inv = c > 0 ? 1.f / (float)c : 0.f;
      unsigned o = (unsigned)f2bf(a0 * inv) | ((unsigned)f2bf(a1 * inv) << 16);
      *(unsigned*)(ldsb + (size_t)r * 8192 + row * 256 + ((lane * 4) ^ sx)) = o;
    }
  }
  __syncthreads();

  int arow = lane & 15, kg = lane >> 4;
  int col = w * 16 + arow;
  f32x4 acc[2];
  acc[0] = (f32x4){0.f, 0.f, 0.f, 0.f};
  acc[1] = (f32x4){0.f, 0.f, 0.f, 0.f};
  #pragma unroll
  for (int s = 0; s < 5; ++s){
    const u16* WT = (s < 4) ? wrel + (size_t)s * 16384 : wroot;
    bf16x8 b[4];
    #pragma unroll
    for (int kk = 0; kk < 4; ++kk)
      b[kk] = *(const bf16x8*)(WT + (size_t)col * H_DIM + kk * 32 + kg * 8);
    #pragma unroll
    for (int rt = 0; rt < 2; ++rt){
      int row = rt * 16 + arow;
      const char* base = (const char*)&lds[s][0][0] + row * 256;
      int sx = (row & 7) << 4;
      #pragma unroll
      for (int kk = 0; kk < 4; ++kk){
        bf16x8 a = *(const bf16x8*)(base + ((kk * 64 + kg * 16) ^ sx));
        acc[rt] = __builtin_amdgcn_mfma_f32_16x16x32_bf16(a, b[kk], acc[rt], 0, 0, 0);
      }
    }
  }
  float bb = bias[col];
  #pragma unroll
  for (int rt = 0; rt < 2; ++rt)
    #pragma unroll
    for (int j = 0; j < 4; ++j){
      int gr = m0 + rt * 16 + kg * 4 + j;
      hbo[(size_t)gr * H_DIM + col] = f2bf(relu_f(acc[rt][j] + bb));
    }
}

// ---------- fused MFConv: in-kernel sum-agg -> LDS, per-degree buckets ----------
template<int FINAL>
__global__ __launch_bounds__(512) void k_mf_fused(const u16* __restrict__ hb,
                                                  const int* __restrict__ row_ptr,
                                                  const int* __restrict__ esrc,
                                                  const u16* __restrict__ wl, const u16* __restrict__ wr,
                                                  const float* __restrict__ bl,
                                                  const int* __restrict__ bcount, const int* __restrict__ boff,
                                                  const int* __restrict__ perm,
                                                  u16* __restrict__ hbo, float* __restrict__ hf){
  __shared__ u16 lds[2][32][128];   // 16 KB: agg + root
  __shared__ int rows_s[32];
  int t = blockIdx.x;
  int d = -1, tile = 0;
  for (int dd = 0; dd <= MAXDEG; ++dd){
    int nt = (bcount[dd] + 31) >> 5;
    if (t < nt){ d = dd; tile = t; break; }
    t -= nt;
  }
  if (d < 0) return;
  int cnt_d = bcount[d];
  int start = boff[d] + tile * 32;
  int nrows = cnt_d - tile * 32; if (nrows > 32) nrows = 32;

  int tid = threadIdx.x;
  int w = tid >> 6, lane = tid & 63;
  if (tid < 32) rows_s[tid] = (tid < nrows) ? perm[start + tid] : -1;

  // stage root rows
  {
    int rg = lane >> 4, cb = (lane & 15) << 4;
    int srow = w * 4 + rg;
    int swcb = cb ^ ((srow & 7) << 4);
    int node = perm[start + (srow < nrows ? srow : 0)];
    gload16(hb + (size_t)node * H_DIM + (swcb >> 1), &lds[1][w * 4][0]);
  }
  // aggregate sums into lds[0]
  #pragma unroll
  for (int i = 0; i < 4; ++i){
    int row = w * 4 + i;
    if (row < nrows){
      int node = perm[start + row];
      int beg = row_ptr[node], end = row_ptr[node + 1];
      float a0 = 0.f, a1 = 0.f;
      int e = beg;
      for (; e + 4 <= end; e += 4){
        int s0 = esrc[e], s1 = esrc[e + 1], s2 = esrc[e + 2], s3 = esrc[e + 3];
        unsigned v0 = *(const unsigned*)(hb + (size_t)s0 * H_DIM + lane * 2);
        unsigned v1 = *(const unsigned*)(hb + (size_t)s1 * H_DIM + lane * 2);
        unsigned v2 = *(const unsigned*)(hb + (size_t)s2 * H_DIM + lane * 2);
        unsigned v3 = *(const unsigned*)(hb + (size_t)s3 * H_DIM + lane * 2);
        a0 += blo(v0) + blo(v1) + blo(v2) + blo(v3);
        a1 += bhi(v0) + bhi(v1) + bhi(v2) + bhi(v3);
      }
      for (; e < end; ++e){
        unsigned v = *(const unsigned*)(hb + (size_t)esrc[e] * H_DIM + lane * 2);
        a0 += blo(v); a1 += bhi(v);
      }
      unsigned o = (unsigned)f2bf(a0) | ((unsigned)f2bf(a1) << 16);
      int sx = (row & 7) << 4;
      *(unsigned*)((char*)&lds[0][0][0] + row * 256 + ((lane * 4) ^ sx)) = o;
    }
  }
  __syncthreads();

  int arow = lane & 15, kg = lane >> 4;
  int col = w * 16 + arow;
  f32x4 acc[2];
  acc[0] = (f32x4){0.f, 0.f, 0.f, 0.f};
  acc[1] = (f32x4){0.f, 0.f, 0.f, 0.f};
  #pragma unroll
  for (int s = 0; s < 2; ++s){
    const u16* WT = (s ? wr : wl) + (size_t)d * 16384;
    bf16x8 b[4];
    #pragma unroll
    for (int kk = 0; kk < 4; ++kk)
      b[kk] = *(const bf16x8*)(WT + (size_t)col * H_DIM + kk * 32 + kg * 8);
    #pragma unroll
    for (int rt = 0; rt < 2; ++rt){
      int row = rt * 16 + arow;
      const char* base = (const char*)&lds[s][0][0] + row * 256;
      int sx = (row & 7) << 4;
      #pragma unroll
      for (int kk = 0; kk < 4; ++kk){
        bf16x8 a = *(const bf16x8*)(base + ((kk * 64 + kg * 16) ^ sx));
        acc[rt] = __builtin_amdgcn_mfma_f32_16x16x32_bf16(a, b[kk], acc[rt], 0, 0, 0);
      }
    }
  }
  float bb = bl[(size_t)d * H_DIM + col];
  #pragma unroll
  for (int rt = 0; rt < 2; ++rt)
    #pragma unroll
    for (int j = 0; j < 4; ++j){
      int gr = rows_s[rt * 16 + kg * 4 + j];
      if (gr >= 0){
        float v = acc[rt][j] + bb;
        if (FINAL) hf[(size_t)gr * H_DIM + col] = v;
        else       hbo[(size_t)gr * H_DIM + col] = f2bf(relu_f(v));
      }
    }
}

// ---------- graph boundaries ----------
__global__ void k_goff(const int* __restrict__ batch, int* __restrict__ goff){
  int n = blockIdx.x * blockDim.x + threadIdx.x;
  if (n >= N_NODES) return;
  int b = batch[n];
  int bp = (n == 0) ? -1 : batch[n - 1];
  for (int g = bp + 1; g <= b; ++g) goff[g] = n;
  if (n == N_NODES - 1){
    for (int g = b + 1; g <= G_GRAPHS; ++g) goff[g] = N_NODES;
  }
}

// ---------- pooling ----------
__global__ __launch_bounds__(256) void k_pool(const float* __restrict__ h, const int* __restrict__ goff,
                                              float* __restrict__ pooled){
  __shared__ float4 sred[8][32];
  int g = blockIdx.x;
  int tid = threadIdx.x;
  int rg = tid >> 5, lane = tid & 31;
  int beg = goff[g], end = goff[g + 1];
  float4 acc = make_float4(0.f, 0.f, 0.f, 0.f);
  for (int n = beg + rg; n < end; n += 8){
    float4 v = ((const float4*)(h + (size_t)n * H_DIM))[lane];
    acc.x += v.x; acc.y += v.y; acc.z += v.z; acc.w += v.w;
  }
  sred[rg][lane] = acc;
  __syncthreads();
  if (tid < 32){
    float4 s = sred[0][tid];
    #pragma unroll
    for (int r = 1; r < 8; ++r){
      float4 v = sred[r][tid];
      s.x += v.x; s.y += v.y; s.z += v.z; s.w += v.w;
    }
    *(float4*)(pooled + (size_t)g * H_DIM + tid * 4) = s;
  }
}

// ---------- MLP ----------
__global__ void k_mlp1(const float* __restrict__ pooled, const float* __restrict__ W1,
                       const float* __restrict__ b1, float* __restrict__ T){
  int t = blockIdx.x * blockDim.x + threadIdx.x;
  if (t >= G_GRAPHS * H_DIM) return;
  int n = t >> 7, j = t & 127;
  float s = b1[j];
  for (int k = 0; k < H_DIM; ++k) s += pooled[n * H_DIM + k] * W1[k * H_DIM + j];
  T[t] = relu_f(s);
}

__global__ void k_mlp2(const float* __restrict__ T, const float* __restrict__ W2,
                       const float* __restrict__ b2, float* __restrict__ out){
  int t = blockIdx.x * blockDim.x + threadIdx.x;
  if (t >= G_GRAPHS * N_OUT) return;
  int n = t / N_OUT, j = t - n * N_OUT;
  float s = b2[j];
  for (int k = 0; k < H_DIM; ++k) s += T[n * H_DIM + k] * W2[k * N_OUT + j];
  out[t] = s;
}

extern "C" void kernel_launch(void* const* d_in, const int* in_sizes, int n_in,
                              void* d_out, int out_size, void* d_ws, size_t ws_size,
                              hipStream_t stream){
  const float* x      = (const float*)d_in[0];
  const int*   ei     = (const int*)d_in[1];
  const int*   ea     = (const int*)d_in[2];
  const int*   batch  = (const int*)d_in[3];
  const float* W0     = (const float*)d_in[4];
  const float* b0     = (const float*)d_in[5];
  const float* rWrel  = (const float*)d_in[6];
  const float* rWroot = (const float*)d_in[7];
  const float* rb     = (const float*)d_in[8];
  const float* mWl    = (const float*)d_in[9];
  const float* mbl    = (const float*)d_in[10];
  const float* mWr    = (const float*)d_in[11];
  const float* W1     = (const float*)d_in[12];
  const float* b1     = (const float*)d_in[13];
  const float* W2     = (const float*)d_in[14];
  const float* b2     = (const float*)d_in[15];
  float* out = (float*)d_out;

  const int* src = ei;
  const int* dst = ei + N_EDGES;

  char* ws = (char*)d_ws;
  size_t off = 0;
  auto alloc = [&](size_t bytes) -> void* {
    void* p = ws + off;
    off += (bytes + 255) & ~(size_t)255;
    return p;
  };
  u16* xb      = (u16*)alloc((size_t)N_NODES * H_DIM * 2);
  u16* hbA     = (u16*)alloc((size_t)N_NODES * H_DIM * 2);
  u16* hbB     = (u16*)alloc((size_t)N_NODES * H_DIM * 2);
  float* hf    = (float*)alloc((size_t)N_NODES * H_DIM * 4);
  u16* wt0     = (u16*)alloc((size_t)1 * 16384 * 2);
  u16* wtRel   = (u16*)alloc((size_t)NBLK * R_REL * 16384 * 2);
  u16* wtRoot  = (u16*)alloc((size_t)NBLK * 16384 * 2);
  u16* wtWl    = (u16*)alloc((size_t)NBLK * (MAXDEG + 1) * 16384 * 2);
  u16* wtWr    = (u16*)alloc((size_t)NBLK * (MAXDEG + 1) * 16384 * 2);
  float* pooled = (float*)alloc((size_t)G_GRAPHS * H_DIM * 4);
  float* T      = (float*)alloc((size_t)G_GRAPHS * H_DIM * 4);
  int* cnt4     = (int*)alloc((size_t)N_NODES * R_REL * 4);
  int* deg      = (int*)alloc((size_t)N_NODES * 4);
  int* row_ptr  = (int*)alloc((size_t)(N_NODES + 1) * 4);
  int* rel_off  = (int*)alloc((size_t)N_NODES * R_REL * 4);
  int* cursor   = (int*)alloc((size_t)N_NODES * R_REL * 4);
  int* esrc     = (int*)alloc((size_t)N_EDGES * 4);
  int* bsum     = (int*)alloc((size_t)NSCAN_BLK * 4);
  int* bbase    = (int*)alloc((size_t)NSCAN_BLK * 4);
  int* bhist    = (int*)alloc((size_t)NSCAN_BLK * (MAXDEG + 1) * 4);
  int* pbase    = (int*)alloc((size_t)NSCAN_BLK * (MAXDEG + 1) * 4);
  int* perm     = (int*)alloc((size_t)N_NODES * 4);
  int* bcount   = (int*)alloc(16 * 4);
  int* boff     = (int*)alloc(16 * 4);
  int* goff     = (int*)alloc((size_t)(G_GRAPHS + 1) * 4);

  hipMemsetAsync(cnt4, 0, (size_t)N_NODES * R_REL * 4, stream);

  // graph structure
  k_cnt<<<(N_EDGES + 255) / 256, 256, 0, stream>>>(dst, ea, cnt4);
  k_scan_a<<<NSCAN_BLK, 256, 0, stream>>>(cnt4, deg, row_ptr, bsum, bhist);
  k_scan_b<<<1, 256, 0, stream>>>(bsum, bbase);
  k_scan_c<<<NSCAN_BLK, 256, 0, stream>>>(row_ptr, bbase, cnt4, rel_off, cursor);
  k_csr_fill<<<(N_EDGES + 255) / 256, 256, 0, stream>>>(src, dst, ea, cursor, esrc);
  k_bscan<<<1, 64, 0, stream>>>(bhist, pbase, bcount, boff);
  k_bfill<<<NSCAN_BLK, 256, 0, stream>>>(deg, pbase, perm);
  k_goff<<<(N_NODES + 255) / 256, 256, 0, stream>>>(batch, goff);

  // weight + input conversion
  k_cvtW_all<<<55 * 16, 256, 0, stream>>>(W0, rWrel, rWroot, mWl, mWr,
                                          wt0, wtRel, wtRoot, wtWl, wtWr);
  k_cvtx<<<(N_NODES * H_DIM / 4 + 255) / 256, 256, 0, stream>>>(x, xb);

  k_gemm0<<<N_NODES / 32, 512, 0, stream>>>(xb, wt0, b0, hbA);

  u16* hin = hbA;
  u16* hout = hbB;
  for (int blk = 0; blk < NBLK; ++blk){
    k_rgcn_fused<<<N_NODES / 32, 512, 0, stream>>>(hin, rel_off, row_ptr, esrc,
        wtRel + (size_t)blk * R_REL * 16384,
        wtRoot + (size_t)blk * 16384,
        rb + (size_t)blk * H_DIM, hout);
    { u16* tmp = hin; hin = hout; hout = tmp; }

    const u16* wl_b = wtWl + (size_t)blk * (MAXDEG + 1) * 16384;
    const u16* wr_b = wtWr + (size_t)blk * (MAXDEG + 1) * 16384;
    const float* bl_b = mbl + (size_t)blk * (MAXDEG + 1) * H_DIM;
    int grid_mf = N_NODES / 32 + MAXDEG + 1;
    if (blk == NBLK - 1)
      k_mf_fused<1><<<grid_mf, 512, 0, stream>>>(hin, row_ptr, esrc, wl_b, wr_b, bl_b,
                                                 bcount, boff, perm, hout, hf);
    else
      k_mf_fused<0><<<grid_mf, 512, 0, stream>>>(hin, row_ptr, esrc, wl_b, wr_b, bl_b,
                                                 bcount, boff, perm, hout, hf);
    { u16* tmp = hin; hin = hout; hout = tmp; }
  }

  k_pool<<<G_GRAPHS, 256, 0, stream>>>(hf, goff, pooled);
  k_mlp1<<<(G_GRAPHS * H_DIM + 255) / 256, 256, 0, stream>>>(pooled, W1, b1, T);
  k_mlp2<<<(G_GRAPHS * N_OUT + 255) / 256, 256, 0, stream>>>(T, W2, b2, out);
}